// Round 5
// baseline (518.184 us; speedup 1.0000x reference)
//
#include <hip/hip_runtime.h>

// Fused tanh-RNN: h_{t+1} = tanh(x_t @ W_ih^T + b_ih + b_hh + h_t @ W_hh^T)
// out = h_T @ W_out^T + b_out.  B=4096, T=512, I=28, H=64, O=10.
//
// R5 (from R4's 240 us kernel, VALUBusy 46 / Mfma 13 / ~40% stall):
//  - ROWS=8, 512 blocks, 4 waves each -> 2 blocks/CU = 2 INDEPENDENT waves
//    per SIMD with SEPARATE hw barriers. One block's post-barrier LDS-read
//    latency / trans-pipe time is filled by the other block's issue. MFMA
//    rows 8..15 duplicate the next block's rows (clamped at B-1) — MFMA
//    issue is cheap (13%), stall-fill is the win.
//  - h stored in LDS PRE-SPLIT as bf16 hi/lo in A-operand layout (short
//    buffers, row stride 72 = 144B, 16B-aligned). Write = 8x ds_write_b16
//    (+16 VALU, pre-barrier); read = 4x ds_read_b128 straight into MFMA
//    fragments — ZERO post-barrier VALU (R4 spent ~40 ops re-splitting).
//    Bit-identical numerics (same hi/lo split, applied pre-store).
//  - Kept from R1-R4: bf16x3 operand split (absmax 0.0039 vs thr 0.0255),
//    lgkmcnt-only barrier (global x prefetch stays in flight), 4-slot x
//    register pipeline with static renaming, bias as MFMA C operand.

#define T_STEPS 512
#define I_DIM   28
#define H_DIM   64
#define O_DIM   10
#define ROWS    8            // useful batch rows per block (MFMA computes 16)
#define HSTR    72           // shorts per h row: 144B = 9*16 -> b128-aligned rows
#define HELE    (16 * HSTR)  // one h buffer (16 rows incl. duplicated top half)

typedef __attribute__((ext_vector_type(8))) short bfrag;   // 8 x bf16 (4 VGPRs)
typedef __attribute__((ext_vector_type(4))) float ffrag;   // MFMA C/D
typedef __attribute__((ext_vector_type(4))) float float4v;

#define MFMA(a,b,c) __builtin_amdgcn_mfma_f32_16x16x32_bf16((a),(b),(c),0,0,0)
// Workgroup barrier draining ONLY LDS ops (inter-wave deps are LDS-only);
// global vmcnt loads legally stay outstanding across it.
#define LDS_BARRIER() asm volatile("s_waitcnt lgkmcnt(0)\n\ts_barrier" ::: "memory")

union FragU { bfrag s; unsigned u[4]; };

__device__ __forceinline__ unsigned hi_pack(float f0, float f1){
  return __builtin_amdgcn_perm(__float_as_uint(f1), __float_as_uint(f0), 0x07060302u);
}

// fp32 -> (hi bf16, lo bf16) fragments, v = hi + lo up to ~2^-16 rel
__device__ __forceinline__ void split8v(float4v a, float4v b, bfrag& hi, bfrag& lo){
  float f[8] = {a.x,a.y,a.z,a.w, b.x,b.y,b.z,b.w};
  FragU H, L;
#pragma unroll
  for (int m = 0; m < 4; m++){
    float f0 = f[2*m], f1 = f[2*m+1];
    H.u[m] = hi_pack(f0, f1);
    float l0 = f0 - __uint_as_float(__float_as_uint(f0) & 0xffff0000u);
    float l1 = f1 - __uint_as_float(__float_as_uint(f1) & 0xffff0000u);
    L.u[m] = hi_pack(l0, l1);
  }
  hi = H.s; lo = L.s;
}

__device__ __forceinline__ float fast_tanh(float p){
  // tanh(p) = 1 - 2/(exp2(2*log2e*p)+1); saturates correctly for large |p|.
  float e = __builtin_amdgcn_exp2f(p * 2.88539008177792681f);
  return __builtin_fmaf(-2.0f, __builtin_amdgcn_rcpf(e + 1.0f), 1.0f);
}

// One RNN step for one wave (its 16 hidden cols). XA/XB consumed then
// overwritten with the t+4 load (static renaming, no rotation movs).
// BUF_OFF: h double-buffer half WRITTEN this step (read back for t+1).
#define BODY(T_C, XA, XB, BUF_OFF)                                             \
  {                                                                            \
    bfrag xhi, xlo;                                                            \
    split8v(XA, XB, xhi, xlo);                                                 \
    {                                                                          \
      int tload = (T_C) + 4; if (tload > T_STEPS - 1) tload = T_STEPS - 1;     \
      const float* lp = xrow + (size_t)tload * I_DIM;                          \
      XA = *(const float4v*)lp;                                                \
      XB = *(const float4v*)(qlt3 ? lp + 4 : lp);                              \
    }                                                                          \
    ffrag acA, acB;                                                            \
    /* x projection: off the h critical path (x ready 4 steps early) */        \
    acA = MFMA(xhi, wih_hi, biasf);                                            \
    acB = MFMA(xhi, wih_lo, zfrag);                                            \
    acA = MFMA(xlo, wih_hi, acA);                                              \
    /* h recurrence: 2 chains, depth 3 from h-ready */                         \
    acA = MFMA(h_hi[0], whh_hi[0], acA);                                       \
    acB = MFMA(h_hi[1], whh_hi[1], acB);                                       \
    acA = MFMA(h_lo[0], whh_hi[0], acA);                                       \
    acB = MFMA(h_lo[1], whh_hi[1], acB);                                       \
    acA = MFMA(h_hi[0], whh_lo[0], acA);                                       \
    acB = MFMA(h_hi[1], whh_lo[1], acB);                                       \
    /* tanh -> split -> b16 stores in A-layout (rows q*4+e, col c+16w) */      \
    float fv[4];                                                               \
    fv[0] = fast_tanh(acA.x + acB.x);                                          \
    fv[1] = fast_tanh(acA.y + acB.y);                                          \
    fv[2] = fast_tanh(acA.z + acB.z);                                          \
    fv[3] = fast_tanh(acA.w + acB.w);                                          \
    short* wH = hHi + (BUF_OFF) + (q*4)*HSTR + (c + 16*w);                     \
    short* wL = hLo + (BUF_OFF) + (q*4)*HSTR + (c + 16*w);                     \
    _Pragma("unroll")                                                          \
    for (int e = 0; e < 4; ++e){                                               \
      unsigned u = __float_as_uint(fv[e]);                                     \
      wH[e*HSTR] = (short)(u >> 16);                                           \
      float rem = fv[e] - __uint_as_float(u & 0xffff0000u);                    \
      wL[e*HSTR] = (short)(__float_as_uint(rem) >> 16);                        \
    }                                                                          \
    LDS_BARRIER();                                                             \
    /* reload h(t+1) A-frags: 4x ds_read_b128, ZERO post-barrier VALU */       \
    const short* rH = hHi + (BUF_OFF) + c*HSTR + q*8;                          \
    const short* rL = hLo + (BUF_OFF) + c*HSTR + q*8;                          \
    h_hi[0] = *(const bfrag*)rH;  h_hi[1] = *(const bfrag*)(rH + 32);          \
    h_lo[0] = *(const bfrag*)rL;  h_lo[1] = *(const bfrag*)(rL + 32);          \
  }

__global__ __launch_bounds__(256, 1) void rnn_fused(
    const float* __restrict__ x,
    const float* __restrict__ W_ih,
    const float* __restrict__ W_hh,
    const float* __restrict__ b_ih,
    const float* __restrict__ b_hh,
    const float* __restrict__ W_out,
    const float* __restrict__ b_out,
    float* __restrict__ out,
    int Btot)
{
  __shared__ __attribute__((aligned(16))) short hHi[2 * HELE];
  __shared__ __attribute__((aligned(16))) short hLo[2 * HELE];
  const int tid  = threadIdx.x;
  const int w    = tid >> 6;           // wave id = hidden col tile
  const int lane = tid & 63;
  const int c    = lane & 15;
  const int q    = lane >> 4;
  const bool qlt3 = (q < 3);
  const int rowbase = blockIdx.x * ROWS;

  // ---- this wave's W_hh^T B-fragments (hi/lo): cols c+16w, k=32kt+8q+jj ----
  bfrag whh_hi[2], whh_lo[2];
#pragma unroll
  for (int kt = 0; kt < 2; ++kt){
    const float* p = W_hh + (c + 16*w)*H_DIM + kt*32 + q*8;
    split8v(*(const float4v*)p, *(const float4v*)(p + 4), whh_hi[kt], whh_lo[kt]);
  }

  // ---- this wave's W_ih^T B-fragment, K padded 28 -> 32 with zeros ----
  bfrag wih_hi, wih_lo;
  {
    const float* p = W_ih + (c + 16*w)*I_DIM + q*8;
    float4v a = *(const float4v*)p;                        // i <= 27: in-bounds
    float4v b;
    if (qlt3) b = *(const float4v*)(p + 4);
    else      b = (float4v){0.f, 0.f, 0.f, 0.f};           // i = 28..31 pad
    split8v(a, b, wih_hi, wih_lo);
  }

  // bias as C operand; const-zero C for the second chain
  ffrag biasf;
  {
    float bb = b_ih[c + 16*w] + b_hh[c + 16*w];
    biasf.x = bb; biasf.y = bb; biasf.z = bb; biasf.w = bb;
  }
  const ffrag zfrag = {0.f, 0.f, 0.f, 0.f};

  // h fragments, h0 = 0
  bfrag h_hi[2], h_lo[2];
  {
    FragU Z; Z.u[0]=Z.u[1]=Z.u[2]=Z.u[3]=0;
    h_hi[0] = Z.s; h_lo[0] = Z.s; h_hi[1] = Z.s; h_lo[1] = Z.s;
  }

  // ---- 4-slot x pipeline. A-frag pattern: row r=c, i=q*8+jj. Rows 8..15
  // duplicate the next block's rows; clamp to B-1 so the last block stays
  // in-bounds (their results are never written out). quad 3's upper float4
  // multiplies zero W pad -> clamp pointer.
  int xr = rowbase + c; if (xr > Btot - 1) xr = Btot - 1;
  const float* xrow = x + ((size_t)xr * T_STEPS) * I_DIM + q*8;
  float4v xa[4], xb[4];
#pragma unroll
  for (int s = 0; s < 4; ++s){
    const float* p = xrow + (size_t)s * I_DIM;
    xa[s] = *(const float4v*)p;
    xb[s] = *(const float4v*)(qlt3 ? p + 4 : p);
  }

#pragma unroll 1
  for (int tb = 0; tb < T_STEPS; tb += 4){
    BODY(tb + 0, xa[0], xb[0], HELE);   // t even -> buf 1
    BODY(tb + 1, xa[1], xb[1], 0);      // t odd  -> buf 0
    BODY(tb + 2, xa[2], xb[2], HELE);
    BODY(tb + 3, xa[3], xb[3], 0);
  }

  // epilogue: final h (t=511 wrote buf 0) -> out, rows c < ROWS only.
  // h[r][k] = bf16(hi) + bf16(lo) reconstructed in fp32.
  if (w == 0 && c < ROWS){
    for (int oo = q; oo < O_DIM; oo += 4){
      float s = b_out[oo];
#pragma unroll 8
      for (int k = 0; k < H_DIM; ++k){
        float hv = __uint_as_float(((unsigned)(unsigned short)hHi[c*HSTR + k]) << 16)
                 + __uint_as_float(((unsigned)(unsigned short)hLo[c*HSTR + k]) << 16);
        s += hv * W_out[oo*H_DIM + k];
      }
      out[(size_t)(rowbase + c)*O_DIM + oo] = s;
    }
  }
}

extern "C" void kernel_launch(void* const* d_in, const int* in_sizes, int n_in,
                              void* d_out, int out_size, void* d_ws, size_t ws_size,
                              hipStream_t stream) {
  const float* x     = (const float*)d_in[0];
  const float* W_ih  = (const float*)d_in[1];
  const float* W_hh  = (const float*)d_in[2];
  const float* b_ih  = (const float*)d_in[3];
  const float* b_hh  = (const float*)d_in[4];
  const float* W_out = (const float*)d_in[5];
  const float* b_out = (const float*)d_in[6];
  float* out = (float*)d_out;

  int B = in_sizes[0] / (T_STEPS * I_DIM);   // 4096
  rnn_fused<<<B / ROWS, 256, 0, stream>>>(x, W_ih, W_hh, b_ih, b_hh, W_out, b_out, out, B);
}